// Round 1
// baseline (301.757 us; speedup 1.0000x reference)
//
#include <hip/hip_runtime.h>

// TileWarping: B=4, C=16, H=512, W=960, UP=4 -> out [4, 48, 128, 240] f32.
// R2 design: barrier-free direct gather.
//  - Previous (R1) version staged fea_r rows in LDS behind two vmcnt(0)
//    barrier drains; 15-wave blocks capped co-residency at 2 blocks/CU, so
//    the drains serialized (all counters <20% busy). This version removes
//    LDS and barriers entirely.
//  - The 3 disp_d variants share fractional weights; all 6 bilinear taps
//    live at columns p..p+3. Each tap column is clamped to [0, W) so the
//    4 global dword loads are always in-bounds; out-of-image taps get
//    zero WEIGHT (channel-invariant), so clamped garbage reads are safe.
//    Adjacent threads' tap windows overlap heavily -> L1/L2 absorb the 4x
//    read amplification; HBM traffic stays at compulsory reads.
//  - 320-thread blocks (5 waves), no LDS, ~40 VGPR -> ~30 waves/CU, every
//    wave independently pipelines its 80 loads. Latency hidden by TLP+ILP.

#define NB 4
#define NC 16
#define NH 512
#define NW 960
#define TH 128
#define TW 240
#define HW (NH * NW)

__global__ __launch_bounds__(320, 8) void tile_warp_kernel(
    const float* __restrict__ tp,   // [B,3,128,240]
    const float* __restrict__ fl,   // [B,16,512,960]
    const float* __restrict__ fr,   // [B,16,512,960]
    float* __restrict__ out)        // [B,48,128,240]
{
    const int u = blockIdx.x * 320 + threadIdx.x;  // column 0..959
    const int Y = blockIdx.y;                      // full-res row 0..511
    const int b = blockIdx.z;                      // batch 0..3
    const int y = Y >> 2, i = Y & 3;
    const int T = u >> 2, j = u & 3;

    const float* frrow = fr + (size_t)(b * NC) * HW + (size_t)Y * NW;
    const float* flrow = fl + (size_t)(b * NC) * HW + (size_t)Y * NW + u;

    // ---- per-thread setup (identical arithmetic to R1) ----
    const int tpb = (b * 3 * TH + y) * TW + T;
    const float d   = tp[tpb];
    const float dxv = tp[tpb + TH * TW];
    const float dyv = tp[tpb + 2 * TH * TW];
    const float base = d + ((float)i - 1.5f) * dyv + ((float)j - 1.5f) * dxv;
    const float xf  = (float)u - base;             // kk=1 (disp_d = 0)
    const float x0f = floorf(xf);
    const float w1  = xf - x0f;
    const float w0  = 1.0f - w1;
    const int   x0  = (int)x0f;
    const int   p   = x0 - 1;                      // taps at x = p .. p+3

    // per-variant masked weights: wv_kk = m[2-kk]*w0k[kk] + m[3-kk]*w1k[kk]
    float w0k[3], w1k[3];
#pragma unroll
    for (int kk = 0; kk < 3; ++kk) {
        const int xa = p + 2 - kk;                 // g0 tap
        const int xb = p + 3 - kk;                 // g1 tap
        w0k[kk] = (xa >= 0 && xa < NW) ? w0 : 0.0f;
        w1k[kk] = (xb >= 0 && xb < NW) ? w1 : 0.0f;
    }

    // clamped tap columns: always-legal addresses; OOB taps have zero weight
    const int i0 = min(max(p    , 0), NW - 1);
    const int i1 = min(max(p + 1, 0), NW - 1);
    const int i2 = min(max(p + 2, 0), NW - 1);
    const int i3 = min(max(p + 3, 0), NW - 1);

    float acc0 = 0.f, acc1 = 0.f, acc2 = 0.f;

#pragma unroll
    for (int c = 0; c < NC; ++c) {
        const float* frc = frrow + (size_t)c * HW;
        const float m0  = frc[i0];
        const float m1  = frc[i1];
        const float m2  = frc[i2];
        const float m3  = frc[i3];
        const float flv = flrow[(size_t)c * HW];
        const float wv0 = m2 * w0k[0] + m3 * w1k[0];
        const float wv1 = m1 * w0k[1] + m2 * w1k[1];
        const float wv2 = m0 * w0k[2] + m1 * w1k[2];
        acc0 += fabsf(flv - wv0);
        acc1 += fabsf(flv - wv1);
        acc2 += fabsf(flv - wv2);
    }

    // ---- store: ch = kk*16 + i*4 + j ----
    const size_t obase = ((size_t)(b * 48 + i * 4 + j) * TH + y) * TW + T;
    out[obase]                        = acc0;
    out[obase + 16 * (size_t)TH * TW] = acc1;
    out[obase + 32 * (size_t)TH * TW] = acc2;
}

extern "C" void kernel_launch(void* const* d_in, const int* in_sizes, int n_in,
                              void* d_out, int out_size, void* d_ws, size_t ws_size,
                              hipStream_t stream) {
    const float* tp = (const float*)d_in[0];
    const float* fl = (const float*)d_in[1];
    const float* fr = (const float*)d_in[2];
    float* out = (float*)d_out;

    dim3 grid(3, NH, NB);   // 3 segments x 512 rows x 4 batches
    dim3 block(320);        // 5 waves, thread -> one output pixel column
    tile_warp_kernel<<<grid, block, 0, stream>>>(tp, fl, fr, out);
}